// Round 7
// baseline (86.524 us; speedup 1.0000x reference)
//
#include <hip/hip_runtime.h>

#define N_GRAPHS 128
#define NODES_PER 400
#define EDGES_PER 6400
#define N_NODES (N_GRAPHS * NODES_PER)   // 51200
#define N_EDGES (N_GRAPHS * EDGES_PER)   // 819200
#define F_IN 256
#define HID 64
#define FEAT 96                          // K * 4 * D = 8*4*3

typedef __attribute__((ext_vector_type(8))) short bf16x8;   // MFMA A/B frag (4 VGPRs)
typedef __attribute__((ext_vector_type(4))) float f32x4;    // MFMA C/D frag

union u4b8 { uint4 u; bf16x8 v; };

// float -> bf16 round-to-nearest-even (finite inputs only)
__device__ __forceinline__ unsigned short f2b(float f) {
  union { float f; unsigned int u; } c; c.f = f;
  const unsigned int r = c.u + 0x7FFFu + ((c.u >> 16) & 1u);
  return (unsigned short)(r >> 16);
}

// async global->LDS DMA, 16B per lane. LDS dest is WAVE-UNIFORM base
// (+ lane*16 added by HW); global src is per-lane.
__device__ __forceinline__ void gload16(const void* g, void* l) {
  __builtin_amdgcn_global_load_lds(
      (const __attribute__((address_space(1))) unsigned int*)g,
      (__attribute__((address_space(3))) unsigned int*)l, 16, 0, 0);
}

// ---------------------------------------------------------------------------
// coordinate transform: one (fun, d) feature for persistence pair (x0, x1)
// ---------------------------------------------------------------------------
__device__ __forceinline__ float coord_one(
    int fun, int d, float x0, float x1,
    const float* __restrict__ t_tri, const float* __restrict__ t_gau,
    const float* __restrict__ sig, const float* __restrict__ W_lin,
    const float* __restrict__ b_lin, const float* __restrict__ c_rh,
    const float* __restrict__ r_rh) {
  if (fun == 0) {
    return fmaxf(x1 - fabsf(t_tri[d] - x0), 0.f);
  } else if (fun == 1) {
    const float dx = x0 - t_gau[d * 2 + 0];
    const float dy = x1 - t_gau[d * 2 + 1];
    const float s = sig[0];
    return expf(-(dx * dx + dy * dy) / (2.f * s * s));
  } else if (fun == 2) {
    return x0 * W_lin[d] + x1 * W_lin[3 + d] + b_lin[d];
  } else {
    const float l1 = fabsf(x0 - c_rh[d]) + fabsf(x1 - c_rh[d]);
    return 1.f / (1.f + l1) - 1.f / (1.f + fabsf(fabsf(r_rh[0]) - l1));
  }
}

// ---------------------------------------------------------------------------
// Kernel 0: chunked bf16 B operands.
//   Wt2 : (k,c) of W_out^T at [((k>>3)*256 + c)*8 + (k&7)], K padded to 384
//         (rows 352..383 = 0; bias + g1 segment folded into G elsewhere)
//   Wt1c: (k,c) of W1^T    at [((k>>3)*64  + c)*8 + (k&7)]
// ---------------------------------------------------------------------------
__global__ __launch_bounds__(256) void k_wt(
    const float* __restrict__ W_out, const float* __restrict__ W1,
    unsigned short* __restrict__ Wt2, unsigned short* __restrict__ Wt1c) {
  const int idx = blockIdx.x * 256 + threadIdx.x;
  if (idx < 384 * 256) {
    const int k = idx >> 8, c = idx & 255;
    const float v = (k < 352) ? W_out[(size_t)k * 256 + c] : 0.f;
    Wt2[((size_t)(k >> 3) * 256 + c) * 8 + (k & 7)] = f2b(v);
  } else {
    const int j = idx - 384 * 256;        // < 256*64
    const int k = j >> 6, c = j & 63;     // W1[k][c]
    Wt1c[((size_t)(k >> 3) * 64 + c) * 8 + (k & 7)] = f2b(W1[j]);
  }
}

// ---------------------------------------------------------------------------
// Kernel 1: fv = relu(relu(x @ W1 + b1) @ W2 + b2), fused with xb + ext.
// (reg A-frags, per-wave B from L2-resident Wt1c; near HBM floor)
// ---------------------------------------------------------------------------
__global__ __launch_bounds__(256, 3) void k_fv(
    const float* __restrict__ x, const unsigned short* __restrict__ Wt1c,
    const float* __restrict__ b1, const float* __restrict__ W2,
    const float* __restrict__ b2,
    const float* __restrict__ t_tri, const float* __restrict__ t_gau,
    const float* __restrict__ sig, const float* __restrict__ W_lin,
    const float* __restrict__ b_lin, const float* __restrict__ c_rh,
    const float* __restrict__ r_rh,
    float* __restrict__ fv, unsigned short* __restrict__ ext,
    unsigned short* __restrict__ xb, const int write_xb) {
  __shared__ float W2s[HID * 8];
  __shared__ float Hs[4][16][68];
  const int tid = threadIdx.x;
  const int wave = tid >> 6, lane = tid & 63;
  const int l15 = lane & 15, l4 = lane >> 4;
  const int n0 = blockIdx.x * 64;

  W2s[tid] = W2[tid];
  W2s[tid + 256] = W2[tid + 256];
  __syncthreads();

  const int arow = n0 + wave * 16 + l15;
  bf16x8 afr[8];
  #pragma unroll
  for (int kt = 0; kt < 8; ++kt) {
    const size_t go = (size_t)arow * F_IN + kt * 32 + l4 * 8;
    const float4 f0 = *(const float4*)&x[go];
    const float4 f1 = *(const float4*)&x[go + 4];
    u4b8 w;
    w.u.x = (unsigned)f2b(f0.x) | ((unsigned)f2b(f0.y) << 16);
    w.u.y = (unsigned)f2b(f0.z) | ((unsigned)f2b(f0.w) << 16);
    w.u.z = (unsigned)f2b(f1.x) | ((unsigned)f2b(f1.y) << 16);
    w.u.w = (unsigned)f2b(f1.z) | ((unsigned)f2b(f1.w) << 16);
    if (write_xb) *(uint4*)&xb[go] = w.u;
    afr[kt] = w.v;
  }

  f32x4 acc[4];
  #pragma unroll
  for (int nf = 0; nf < 4; ++nf) acc[nf] = (f32x4){0.f, 0.f, 0.f, 0.f};
  #pragma unroll
  for (int kt = 0; kt < 8; ++kt) {
    const unsigned short* wb = Wt1c + (size_t)(kt * 4 + l4) * 512;
    #pragma unroll
    for (int nf = 0; nf < 4; ++nf) {
      const bf16x8 b = *(const bf16x8*)&wb[(nf * 16 + l15) * 8];
      acc[nf] = __builtin_amdgcn_mfma_f32_16x16x32_bf16(afr[kt], b, acc[nf], 0, 0, 0);
    }
  }

  #pragma unroll
  for (int nf = 0; nf < 4; ++nf) {
    const int col = nf * 16 + l15;
    const float bb = b1[col];
    #pragma unroll
    for (int j = 0; j < 4; ++j)
      Hs[wave][l4 * 4 + j][col] = fmaxf(acc[nf][j] + bb, 0.f);
  }
  __syncthreads();

  #pragma unroll
  for (int p = tid; p < 512; p += 256) {
    const int row = p >> 3, kk = p & 7;
    const float* hr = Hs[row >> 4][row & 15];
    float s = b2[kk];
    #pragma unroll 8
    for (int j = 0; j < HID; ++j) s = fmaf(hr[j], W2s[j * 8 + kk], s);
    s = fmaxf(s, 0.f);
    const int n = n0 + row;
    fv[(size_t)n * 8 + kk] = s;

    unsigned short o[12] __attribute__((aligned(16)));
    #pragma unroll
    for (int fun = 0; fun < 4; ++fun)
      #pragma unroll
      for (int d = 0; d < 3; ++d)
        o[fun * 3 + d] = f2b(coord_one(fun, d, s, s,
                             t_tri, t_gau, sig, W_lin, b_lin, c_rh, r_rh));
    unsigned short* dst = &ext[(size_t)n * FEAT + kk * 12];
    *(uint2*)&dst[0] = *(const uint2*)&o[0];
    *(uint2*)&dst[4] = *(const uint2*)&o[4];
    *(uint2*)&dst[8] = *(const uint2*)&o[8];
  }
}

// ---------------------------------------------------------------------------
// Kernel 2: unpaired via LDS-staged fv slab.
// ---------------------------------------------------------------------------
#define CHUNK (EDGES_PER / 8)   // 800
__global__ __launch_bounds__(256) void k_unpaired(
    const int* __restrict__ ei, const float* __restrict__ fv,
    float* __restrict__ unp) {
  __shared__ float lfv[NODES_PER * 8];
  __shared__ float red[256][8];
  const int g = blockIdx.x >> 3, ch = blockIdx.x & 7;
  const int tid = threadIdx.x;

  for (int i = tid; i < NODES_PER * 2; i += 256)
    *(float4*)&lfv[i * 4] = *(const float4*)&fv[(size_t)g * NODES_PER * 8 + i * 4];
  __syncthreads();

  float lm[8];
  #pragma unroll
  for (int k = 0; k < 8; ++k) lm[k] = 0.f;
  const int e0 = g * EDGES_PER + ch * CHUNK;
  for (int e = e0 + tid; e < e0 + CHUNK; e += 256) {
    const int a = ei[e] - g * NODES_PER;
    const int b = ei[N_EDGES + e] - g * NODES_PER;
    const float4 a0 = *(const float4*)&lfv[a * 8];
    const float4 a1 = *(const float4*)&lfv[a * 8 + 4];
    const float4 b0 = *(const float4*)&lfv[b * 8];
    const float4 b1 = *(const float4*)&lfv[b * 8 + 4];
    lm[0] = fmaxf(lm[0], fmaxf(a0.x, b0.x));
    lm[1] = fmaxf(lm[1], fmaxf(a0.y, b0.y));
    lm[2] = fmaxf(lm[2], fmaxf(a0.z, b0.z));
    lm[3] = fmaxf(lm[3], fmaxf(a0.w, b0.w));
    lm[4] = fmaxf(lm[4], fmaxf(a1.x, b1.x));
    lm[5] = fmaxf(lm[5], fmaxf(a1.y, b1.y));
    lm[6] = fmaxf(lm[6], fmaxf(a1.z, b1.z));
    lm[7] = fmaxf(lm[7], fmaxf(a1.w, b1.w));
  }
  #pragma unroll
  for (int k = 0; k < 8; ++k) red[tid][k] = lm[k];
  __syncthreads();
  for (int s = 128; s > 0; s >>= 1) {
    if (tid < s) {
      #pragma unroll
      for (int k = 0; k < 8; ++k)
        red[tid][k] = fmaxf(red[tid][k], red[tid + s][k]);
    }
    __syncthreads();
  }
  if (tid < 8)
    atomicMax((int*)&unp[g * 8 + tid], __float_as_int(red[0][tid]));
}

// ---------------------------------------------------------------------------
// Kernel 3: G[g][c] = b_out[c] + sum_t feat1[g][t] * W_out[352+t][c]
// ---------------------------------------------------------------------------
__global__ __launch_bounds__(256) void k_g1G(
    const float* __restrict__ unp, const float* __restrict__ t_tri,
    const float* __restrict__ t_gau, const float* __restrict__ sig,
    const float* __restrict__ W_lin, const float* __restrict__ b_lin,
    const float* __restrict__ c_rh, const float* __restrict__ r_rh,
    const float* __restrict__ W_out, const float* __restrict__ b_out,
    float* __restrict__ G) {
  const int g = blockIdx.x;
  const int t = threadIdx.x;  // 0..255
  __shared__ float u[8];
  __shared__ float feat[96];
  if (t < 8) u[t] = unp[g * 8 + t];
  __syncthreads();
  if (t < 96) {
    const float mask = (u[0] != 0.f || u[1] != 0.f || u[2] != 0.f ||
                        u[3] != 0.f || u[4] != 0.f || u[5] != 0.f ||
                        u[6] != 0.f || u[7] != 0.f) ? 1.f : 0.f;
    const int k = t / 12;
    const int fun = (t % 12) / 3;
    const int d = t % 3;
    feat[t] = mask * coord_one(fun, d, u[k], 0.f,
                               t_tri, t_gau, sig, W_lin, b_lin, c_rh, r_rh);
  }
  __syncthreads();
  float s = b_out[t];
  #pragma unroll 4
  for (int f = 0; f < 96; ++f)
    s = fmaf(feat[f], W_out[(size_t)(352 + f) * 256 + t], s);
  G[g * 256 + t] = s;
}

// ---------------------------------------------------------------------------
// Kernel 4: out = relu([x|act0] @ W_out[0:352] + G[batch])  via MFMA.
// 2-phase double-buffered pipeline (T3-minimum template):
//   per kt: STAGE(kt+1 -> buf^1) via gload_lds DMA; compute kt from buf
//   (ds_read waits lgkm only, NOT vmcnt); ONE __syncthreads per kt drains
//   the prefetch AFTER it has been covered by compute.
// BM=64, BN=256, BK=64, 6 kt (K padded to 384). 512 threads, 8 waves
// (2M x 4N; per-wave 32 rows x 64 cols, 16 MFMA/kt). LDS 82 KB -> 1 blk/CU,
// 2 waves/SIMD. Pad chunk (kt=5, ks=1) MFMAs skipped (B rows zero).
// ---------------------------------------------------------------------------
__global__ __launch_bounds__(512, 1) void k_out_mfma(
    const float* __restrict__ x, const unsigned short* __restrict__ xb,
    const unsigned short* __restrict__ ext, const unsigned short* __restrict__ zpad,
    const unsigned short* __restrict__ Wt2, const float* __restrict__ G,
    float* __restrict__ out, const int use_xb) {
  __shared__ unsigned short As[2][64 * 64];      // 2 x 8 KB
  __shared__ unsigned short Bs[2][8][258][8];    // 2 x 33 KB
  const int tid = threadIdx.x;
  const int wave = tid >> 6, lane = tid & 63;
  const int wr = wave >> 2, wc = wave & 3;
  const int l15 = lane & 15, l4 = lane >> 4;
  const int n0 = blockIdx.x * 64;

  f32x4 acc[2][4];
  #pragma unroll
  for (int i = 0; i < 2; ++i)
    #pragma unroll
    for (int j = 0; j < 4; ++j)
      acc[i][j] = (f32x4){0.f, 0.f, 0.f, 0.f};

  // ---- STAGE(kt -> buffer BUF): A 8 DMAs (1/wave), B 32 DMAs (4/wave) ----
  #define STAGE(KT, BUF)                                                     \
    if (use_xb) {                                                            \
      {                                                                      \
        const int r = wave * 8 + (lane >> 3);                                \
        const int slot = lane & 7;                                           \
        const int c8 = slot ^ (r & 7);                                       \
        const int col = (KT) * 64 + c8 * 8;                                  \
        const int n = n0 + r;                                                \
        const unsigned short* src =                                          \
            (col < 256) ? &xb[(size_t)n * 256 + col]                         \
          : (col < 352) ? &ext[(size_t)n * FEAT + (col - 256)]               \
                        : &zpad[slot * 8];                                   \
        gload16(src, &As[BUF][wave * 512]);                                  \
      }                                                                      \
      _Pragma("unroll")                                                      \
      for (int i = 0; i < 4; ++i) {                                          \
        const int cB = wave * 4 + i;                                         \
        const int kcl = cB >> 2, cg = cB & 3;                                \
        const unsigned short* src =                                          \
            &Wt2[((size_t)((KT) * 8 + kcl) * 256 + cg * 64) * 8 + lane * 8]; \
        gload16(src, &Bs[BUF][kcl][cg * 64][0]);                             \
      }                                                                      \
    } else {                                                                 \
      {                                                                      \
        const int r = tid >> 3, slot = tid & 7;                              \
        const int c8 = slot ^ (r & 7);                                       \
        const int col = (KT) * 64 + c8 * 8;                                  \
        const int n = n0 + r;                                                \
        uint4 w;                                                             \
        if (col < 256) {                                                     \
          const float4 f0 = *(const float4*)&x[(size_t)n * 256 + col];       \
          const float4 f1 = *(const float4*)&x[(size_t)n * 256 + col + 4];   \
          w.x = (unsigned)f2b(f0.x) | ((unsigned)f2b(f0.y) << 16);           \
          w.y = (unsigned)f2b(f0.z) | ((unsigned)f2b(f0.w) << 16);           \
          w.z = (unsigned)f2b(f1.x) | ((unsigned)f2b(f1.y) << 16);           \
          w.w = (unsigned)f2b(f1.z) | ((unsigned)f2b(f1.w) << 16);           \
        } else if (col < 352) {                                              \
          w = *(const uint4*)&ext[(size_t)n * FEAT + (col - 256)];           \
        } else {                                                             \
          w = (uint4){0u, 0u, 0u, 0u};                                       \
        }                                                                    \
        *(uint4*)&As[BUF][tid * 8] = w;                                      \
      }                                                                      \
      _Pragma("unroll")                                                      \
      for (int i = 0; i < 4; ++i) {                                          \
        const int cB = wave * 4 + i;                                         \
        const int kcl = cB >> 2, cg = cB & 3;                                \
        *(uint4*)&Bs[BUF][kcl][cg * 64 + lane][0] =                          \
            *(const uint4*)&Wt2[((size_t)((KT) * 8 + kcl) * 256 +            \
                                 cg * 64) * 8 + lane * 8];                   \
      }                                                                      \
    }

  STAGE(0, 0);
  __syncthreads();

  #pragma unroll
  for (int kt = 0; kt < 6; ++kt) {
    const int buf = kt & 1;
    if (kt < 5) { STAGE(kt + 1, buf ^ 1); }

    #pragma unroll
    for (int ks = 0; ks < 2; ++ks) {
      if (kt == 5 && ks == 1) continue;   // zero-pad chunk: B rows are 0
      bf16x8 a[2], b[4];
      #pragma unroll
      for (int mf = 0; mf < 2; ++mf) {
        const int rl = wr * 32 + mf * 16 + l15;
        const int slot = (ks * 4 + l4) ^ (rl & 7);
        a[mf] = *(const bf16x8*)&As[buf][rl * 64 + slot * 8];
      }
      #pragma unroll
      for (int nf = 0; nf < 4; ++nf)
        b[nf] = *(const bf16x8*)&Bs[buf][ks * 4 + l4][wc * 64 + nf * 16 + l15][0];
      #pragma unroll
      for (int mf = 0; mf < 2; ++mf)
        #pragma unroll
        for (int nf = 0; nf < 4; ++nf)
          acc[mf][nf] = __builtin_amdgcn_mfma_f32_16x16x32_bf16(
              a[mf], b[nf], acc[mf][nf], 0, 0, 0);
    }
    __syncthreads();
  }
  #undef STAGE

  // ---- epilogue: add G[graph(row)] (bias + g1 segment), relu, store ----
  #pragma unroll
  for (int mf = 0; mf < 2; ++mf) {
    const int rowb = n0 + wr * 32 + mf * 16 + l4 * 4;
    #pragma unroll
    for (int j = 0; j < 4; ++j) {
      const int row = rowb + j;
      const float* Gr = &G[(row / NODES_PER) * 256];
      #pragma unroll
      for (int nf = 0; nf < 4; ++nf) {
        const int col = wc * 64 + nf * 16 + l15;
        out[(size_t)row * 256 + col] = fmaxf(acc[mf][nf][j] + Gr[col], 0.f);
      }
    }
  }
}

// ---------------------------------------------------------------------------
extern "C" void kernel_launch(void* const* d_in, const int* in_sizes, int n_in,
                              void* d_out, int out_size, void* d_ws, size_t ws_size,
                              hipStream_t stream) {
  const float* x          = (const float*)d_in[0];
  const int*   edge_index = (const int*)d_in[1];
  // d_in[2] = batch_vec (row/400 computed inline), d_in[3] = edge_slices: unused
  const float* W1     = (const float*)d_in[4];
  const float* b1     = (const float*)d_in[5];
  const float* W2     = (const float*)d_in[6];
  const float* b2     = (const float*)d_in[7];
  const float* t_tri0 = (const float*)d_in[8];
  const float* t_gau0 = (const float*)d_in[9];
  const float* sig0   = (const float*)d_in[10];
  const float* W_lin0 = (const float*)d_in[11];
  const float* b_lin0 = (const float*)d_in[12];
  const float* c_rh0  = (const float*)d_in[13];
  const float* r_rh0  = (const float*)d_in[14];
  const float* t_tri1 = (const float*)d_in[15];
  const float* t_gau1 = (const float*)d_in[16];
  const float* sig1   = (const float*)d_in[17];
  const float* W_lin1 = (const float*)d_in[18];
  const float* b_lin1 = (const float*)d_in[19];
  const float* c_rh1  = (const float*)d_in[20];
  const float* r_rh1  = (const float*)d_in[21];
  const float* W_out  = (const float*)d_in[22];
  const float* b_out  = (const float*)d_in[23];
  float* out = (float*)d_out;

  // workspace layout (16B-aligned):
  // fv 1.6M | unp 4K | G 128K | zpad 256 | Wt2 192K | Wt1c 32K | ext 9.8M | xb 26M
  char* base = (char*)d_ws;
  float* fv            = (float*)(base + 0);
  float* unp           = (float*)(base + 1638400);
  float* G             = (float*)(base + 1642496);
  unsigned short* zpad = (unsigned short*)(base + 1773568);
  unsigned short* Wt2  = (unsigned short*)(base + 1773824);
  unsigned short* Wt1c = (unsigned short*)(base + 1970432);
  unsigned short* ext  = (unsigned short*)(base + 2003200);
  unsigned short* xb   = (unsigned short*)(base + 11833600);
  const size_t ws_need_xb = 11833600 + (size_t)N_NODES * F_IN * 2;  // ~38 MB
  const int use_xb = ws_size >= ws_need_xb ? 1 : 0;

  hipMemsetAsync(unp, 0, N_GRAPHS * 8 * sizeof(float), stream);
  hipMemsetAsync(zpad, 0, 256, stream);
  k_wt<<<(384 * 256 + F_IN * HID) / 256, 256, 0, stream>>>(W_out, W1, Wt2, Wt1c);
  k_fv<<<N_NODES / 64, 256, 0, stream>>>(
      x, Wt1c, b1, W2, b2,
      t_tri0, t_gau0, sig0, W_lin0, b_lin0, c_rh0, r_rh0,
      fv, ext, xb, use_xb);
  k_unpaired<<<N_GRAPHS * 8, 256, 0, stream>>>(edge_index, fv, unp);
  k_g1G<<<N_GRAPHS, 256, 0, stream>>>(unp, t_tri1, t_gau1, sig1,
                                      W_lin1, b_lin1, c_rh1, r_rh1,
                                      W_out, b_out, G);
  k_out_mfma<<<N_NODES / 64, 512, 0, stream>>>(x, xb, ext, zpad, Wt2, G,
                                               out, use_xb);
}

// Round 8
// 76.560 us; speedup vs baseline: 1.1301x; 1.1301x over previous
//
#include <hip/hip_runtime.h>

#define N_GRAPHS 128
#define NODES_PER 400
#define EDGES_PER 6400
#define N_NODES (N_GRAPHS * NODES_PER)   // 51200
#define N_EDGES (N_GRAPHS * EDGES_PER)   // 819200
#define F_IN 256
#define HID 64
#define FEAT 96                          // K * 4 * D = 8*4*3
#define KTOT 352                         // 256 + 96 = 11 * 32 exactly

typedef __attribute__((ext_vector_type(8))) short bf16x8;   // MFMA A/B frag (4 VGPRs)
typedef __attribute__((ext_vector_type(4))) float f32x4;    // MFMA C/D frag

union u4b8 { uint4 u; bf16x8 v; };

// float -> bf16 round-to-nearest-even (finite inputs only)
__device__ __forceinline__ unsigned short f2b(float f) {
  union { float f; unsigned int u; } c; c.f = f;
  const unsigned int r = c.u + 0x7FFFu + ((c.u >> 16) & 1u);
  return (unsigned short)(r >> 16);
}

// ---------------------------------------------------------------------------
// coordinate transform: one (fun, d) feature for persistence pair (x0, x1)
// ---------------------------------------------------------------------------
__device__ __forceinline__ float coord_one(
    int fun, int d, float x0, float x1,
    const float* __restrict__ t_tri, const float* __restrict__ t_gau,
    const float* __restrict__ sig, const float* __restrict__ W_lin,
    const float* __restrict__ b_lin, const float* __restrict__ c_rh,
    const float* __restrict__ r_rh) {
  if (fun == 0) {
    return fmaxf(x1 - fabsf(t_tri[d] - x0), 0.f);
  } else if (fun == 1) {
    const float dx = x0 - t_gau[d * 2 + 0];
    const float dy = x1 - t_gau[d * 2 + 1];
    const float s = sig[0];
    return expf(-(dx * dx + dy * dy) / (2.f * s * s));
  } else if (fun == 2) {
    return x0 * W_lin[d] + x1 * W_lin[3 + d] + b_lin[d];
  } else {
    const float l1 = fabsf(x0 - c_rh[d]) + fabsf(x1 - c_rh[d]);
    return 1.f / (1.f + l1) - 1.f / (1.f + fabsf(fabsf(r_rh[0]) - l1));
  }
}

// ---------------------------------------------------------------------------
// Kernel 0: chunked bf16 B operands.
//   Wt2 : (k,c) of W_out^T at [((k>>3)*256 + c)*8 + (k&7)], k < 352
//   Wt1c: (k,c) of W1^T    at [((k>>3)*64  + c)*8 + (k&7)]
// -> B-frag load = one contiguous 16B per lane.
// ---------------------------------------------------------------------------
__global__ __launch_bounds__(256) void k_wt(
    const float* __restrict__ W_out, const float* __restrict__ W1,
    unsigned short* __restrict__ Wt2, unsigned short* __restrict__ Wt1c) {
  const int idx = blockIdx.x * 256 + threadIdx.x;
  if (idx < KTOT * 256) {
    const int k = idx >> 8, c = idx & 255;
    Wt2[((size_t)(k >> 3) * 256 + c) * 8 + (k & 7)] = f2b(W_out[idx]);
  } else {
    const int j = idx - KTOT * 256;       // < 256*64
    const int k = j >> 6, c = j & 63;     // W1[k][c]
    Wt1c[((size_t)(k >> 3) * 64 + c) * 8 + (k & 7)] = f2b(W1[j]);
  }
}

// ---------------------------------------------------------------------------
// Kernel 1: fv = relu(relu(x @ W1 + b1) @ W2 + b2), fused with xb + ext.
// (reg A-frags, per-wave B from L2-resident Wt1c; near HBM floor)
// ---------------------------------------------------------------------------
__global__ __launch_bounds__(256, 3) void k_fv(
    const float* __restrict__ x, const unsigned short* __restrict__ Wt1c,
    const float* __restrict__ b1, const float* __restrict__ W2,
    const float* __restrict__ b2,
    const float* __restrict__ t_tri, const float* __restrict__ t_gau,
    const float* __restrict__ sig, const float* __restrict__ W_lin,
    const float* __restrict__ b_lin, const float* __restrict__ c_rh,
    const float* __restrict__ r_rh,
    float* __restrict__ fv, unsigned short* __restrict__ ext,
    unsigned short* __restrict__ xb, const int write_xb) {
  __shared__ float W2s[HID * 8];
  __shared__ float Hs[4][16][68];
  const int tid = threadIdx.x;
  const int wave = tid >> 6, lane = tid & 63;
  const int l15 = lane & 15, l4 = lane >> 4;
  const int n0 = blockIdx.x * 64;

  W2s[tid] = W2[tid];
  W2s[tid + 256] = W2[tid + 256];
  __syncthreads();

  const int arow = n0 + wave * 16 + l15;
  bf16x8 afr[8];
  #pragma unroll
  for (int kt = 0; kt < 8; ++kt) {
    const size_t go = (size_t)arow * F_IN + kt * 32 + l4 * 8;
    const float4 f0 = *(const float4*)&x[go];
    const float4 f1 = *(const float4*)&x[go + 4];
    u4b8 w;
    w.u.x = (unsigned)f2b(f0.x) | ((unsigned)f2b(f0.y) << 16);
    w.u.y = (unsigned)f2b(f0.z) | ((unsigned)f2b(f0.w) << 16);
    w.u.z = (unsigned)f2b(f1.x) | ((unsigned)f2b(f1.y) << 16);
    w.u.w = (unsigned)f2b(f1.z) | ((unsigned)f2b(f1.w) << 16);
    if (write_xb) *(uint4*)&xb[go] = w.u;
    afr[kt] = w.v;
  }

  f32x4 acc[4];
  #pragma unroll
  for (int nf = 0; nf < 4; ++nf) acc[nf] = (f32x4){0.f, 0.f, 0.f, 0.f};
  #pragma unroll
  for (int kt = 0; kt < 8; ++kt) {
    const unsigned short* wb = Wt1c + (size_t)(kt * 4 + l4) * 512;
    #pragma unroll
    for (int nf = 0; nf < 4; ++nf) {
      const bf16x8 b = *(const bf16x8*)&wb[(nf * 16 + l15) * 8];
      acc[nf] = __builtin_amdgcn_mfma_f32_16x16x32_bf16(afr[kt], b, acc[nf], 0, 0, 0);
    }
  }

  #pragma unroll
  for (int nf = 0; nf < 4; ++nf) {
    const int col = nf * 16 + l15;
    const float bb = b1[col];
    #pragma unroll
    for (int j = 0; j < 4; ++j)
      Hs[wave][l4 * 4 + j][col] = fmaxf(acc[nf][j] + bb, 0.f);
  }
  __syncthreads();

  #pragma unroll
  for (int p = tid; p < 512; p += 256) {
    const int row = p >> 3, kk = p & 7;
    const float* hr = Hs[row >> 4][row & 15];
    float s = b2[kk];
    #pragma unroll 8
    for (int j = 0; j < HID; ++j) s = fmaf(hr[j], W2s[j * 8 + kk], s);
    s = fmaxf(s, 0.f);
    const int n = n0 + row;
    fv[(size_t)n * 8 + kk] = s;

    unsigned short o[12] __attribute__((aligned(16)));
    #pragma unroll
    for (int fun = 0; fun < 4; ++fun)
      #pragma unroll
      for (int d = 0; d < 3; ++d)
        o[fun * 3 + d] = f2b(coord_one(fun, d, s, s,
                             t_tri, t_gau, sig, W_lin, b_lin, c_rh, r_rh));
    unsigned short* dst = &ext[(size_t)n * FEAT + kk * 12];
    *(uint2*)&dst[0] = *(const uint2*)&o[0];
    *(uint2*)&dst[4] = *(const uint2*)&o[4];
    *(uint2*)&dst[8] = *(const uint2*)&o[8];
  }
}

// ---------------------------------------------------------------------------
// Kernel 2: unpaired via LDS-staged fv slab.
// ---------------------------------------------------------------------------
#define CHUNK (EDGES_PER / 8)   // 800
__global__ __launch_bounds__(256) void k_unpaired(
    const int* __restrict__ ei, const float* __restrict__ fv,
    float* __restrict__ unp) {
  __shared__ float lfv[NODES_PER * 8];
  __shared__ float red[256][8];
  const int g = blockIdx.x >> 3, ch = blockIdx.x & 7;
  const int tid = threadIdx.x;

  for (int i = tid; i < NODES_PER * 2; i += 256)
    *(float4*)&lfv[i * 4] = *(const float4*)&fv[(size_t)g * NODES_PER * 8 + i * 4];
  __syncthreads();

  float lm[8];
  #pragma unroll
  for (int k = 0; k < 8; ++k) lm[k] = 0.f;
  const int e0 = g * EDGES_PER + ch * CHUNK;
  for (int e = e0 + tid; e < e0 + CHUNK; e += 256) {
    const int a = ei[e] - g * NODES_PER;
    const int b = ei[N_EDGES + e] - g * NODES_PER;
    const float4 a0 = *(const float4*)&lfv[a * 8];
    const float4 a1 = *(const float4*)&lfv[a * 8 + 4];
    const float4 b0 = *(const float4*)&lfv[b * 8];
    const float4 b1 = *(const float4*)&lfv[b * 8 + 4];
    lm[0] = fmaxf(lm[0], fmaxf(a0.x, b0.x));
    lm[1] = fmaxf(lm[1], fmaxf(a0.y, b0.y));
    lm[2] = fmaxf(lm[2], fmaxf(a0.z, b0.z));
    lm[3] = fmaxf(lm[3], fmaxf(a0.w, b0.w));
    lm[4] = fmaxf(lm[4], fmaxf(a1.x, b1.x));
    lm[5] = fmaxf(lm[5], fmaxf(a1.y, b1.y));
    lm[6] = fmaxf(lm[6], fmaxf(a1.z, b1.z));
    lm[7] = fmaxf(lm[7], fmaxf(a1.w, b1.w));
  }
  #pragma unroll
  for (int k = 0; k < 8; ++k) red[tid][k] = lm[k];
  __syncthreads();
  for (int s = 128; s > 0; s >>= 1) {
    if (tid < s) {
      #pragma unroll
      for (int k = 0; k < 8; ++k)
        red[tid][k] = fmaxf(red[tid][k], red[tid + s][k]);
    }
    __syncthreads();
  }
  if (tid < 8)
    atomicMax((int*)&unp[g * 8 + tid], __float_as_int(red[0][tid]));
}

// ---------------------------------------------------------------------------
// Kernel 3: G[g][c] = b_out[c] + sum_t feat1[g][t] * W_out[352+t][c]
// ---------------------------------------------------------------------------
__global__ __launch_bounds__(256) void k_g1G(
    const float* __restrict__ unp, const float* __restrict__ t_tri,
    const float* __restrict__ t_gau, const float* __restrict__ sig,
    const float* __restrict__ W_lin, const float* __restrict__ b_lin,
    const float* __restrict__ c_rh, const float* __restrict__ r_rh,
    const float* __restrict__ W_out, const float* __restrict__ b_out,
    float* __restrict__ G) {
  const int g = blockIdx.x;
  const int t = threadIdx.x;  // 0..255
  __shared__ float u[8];
  __shared__ float feat[96];
  if (t < 8) u[t] = unp[g * 8 + t];
  __syncthreads();
  if (t < 96) {
    const float mask = (u[0] != 0.f || u[1] != 0.f || u[2] != 0.f ||
                        u[3] != 0.f || u[4] != 0.f || u[5] != 0.f ||
                        u[6] != 0.f || u[7] != 0.f) ? 1.f : 0.f;
    const int k = t / 12;
    const int fun = (t % 12) / 3;
    const int d = t % 3;
    feat[t] = mask * coord_one(fun, d, u[k], 0.f,
                               t_tri, t_gau, sig, W_lin, b_lin, c_rh, r_rh);
  }
  __syncthreads();
  float s = b_out[t];
  #pragma unroll 4
  for (int f = 0; f < 96; ++f)
    s = fmaf(feat[f], W_out[(size_t)(352 + f) * 256 + t], s);
  G[g * 256 + t] = s;
}

// ---------------------------------------------------------------------------
// Kernel 4: out = relu([x|act0] @ W_out[0:352] + G[batch])  via MFMA.
// BARRIER-FREE, LDS-FREE, B-IN-REGISTERS:
//   512 blocks x 4 waves. Wave w owns col-quarter w (64 cols); its whole
//   B-slice (64 cols x K=352 = 44 bf16x8 frags, 176 VGPR) is loaded ONCE
//   from L2-resident Wt2. The block's 4 waves share row-tile t (A rows hit
//   L2 together), grid-striding t += 512 over 3200 16-row tiles.
//   Per tile: 11 contiguous 16B A-loads (xb/ext direct) + 44 MFMA; no
//   syncthreads anywhere -> 2 waves/SIMD TLP hides A latency.
// ---------------------------------------------------------------------------
__global__ __launch_bounds__(256, 2) void k_out_mfma(
    const float* __restrict__ x, const unsigned short* __restrict__ xb,
    const unsigned short* __restrict__ ext,
    const unsigned short* __restrict__ Wt2, const float* __restrict__ G,
    float* __restrict__ out, const int use_xb) {
  const int tid = threadIdx.x;
  const int wave = tid >> 6, lane = tid & 63;
  const int l15 = lane & 15, l4 = lane >> 4;
  const int q = wave;                       // col-quarter owned by this wave

  // ---- load persistent B slice: 44 frags (ks 0..10 x nf 0..3) ----
  bf16x8 b[11][4];
  #pragma unroll
  for (int ks = 0; ks < 11; ++ks)
    #pragma unroll
    for (int nf = 0; nf < 4; ++nf)
      b[ks][nf] = *(const bf16x8*)
          &Wt2[((size_t)(ks * 4 + l4) * 256 + q * 64 + nf * 16 + l15) * 8];

  for (int t = blockIdx.x; t < N_NODES / 16; t += gridDim.x) {
    const int arow = t * 16 + l15;
    const int gidx = t / 25;                // 400 = 25*16: tile within graph

    // ---- A frags: 11 contiguous 16B loads (x | ext segments) ----
    bf16x8 a[11];
    if (use_xb) {
      #pragma unroll
      for (int ks = 0; ks < 8; ++ks)
        a[ks] = *(const bf16x8*)&xb[(size_t)arow * F_IN + ks * 32 + l4 * 8];
    } else {
      #pragma unroll
      for (int ks = 0; ks < 8; ++ks) {
        const size_t go = (size_t)arow * F_IN + ks * 32 + l4 * 8;
        const float4 f0 = *(const float4*)&x[go];
        const float4 f1 = *(const float4*)&x[go + 4];
        u4b8 w;
        w.u.x = (unsigned)f2b(f0.x) | ((unsigned)f2b(f0.y) << 16);
        w.u.y = (unsigned)f2b(f0.z) | ((unsigned)f2b(f0.w) << 16);
        w.u.z = (unsigned)f2b(f1.x) | ((unsigned)f2b(f1.y) << 16);
        w.u.w = (unsigned)f2b(f1.z) | ((unsigned)f2b(f1.w) << 16);
        a[ks] = w.v;
      }
    }
    #pragma unroll
    for (int ks = 8; ks < 11; ++ks)
      a[ks] = *(const bf16x8*)&ext[(size_t)arow * FEAT + (ks - 8) * 32 + l4 * 8];

    // ---- 44 MFMA ----
    f32x4 acc[4];
    #pragma unroll
    for (int nf = 0; nf < 4; ++nf) acc[nf] = (f32x4){0.f, 0.f, 0.f, 0.f};
    #pragma unroll
    for (int ks = 0; ks < 11; ++ks)
      #pragma unroll
      for (int nf = 0; nf < 4; ++nf)
        acc[nf] = __builtin_amdgcn_mfma_f32_16x16x32_bf16(
            a[ks], b[ks][nf], acc[nf], 0, 0, 0);

    // ---- epilogue: + G[graph] (bias + g1 fold), relu, store ----
    #pragma unroll
    for (int nf = 0; nf < 4; ++nf) {
      const int col = q * 64 + nf * 16 + l15;
      const float gv = G[gidx * 256 + col];
      #pragma unroll
      for (int j = 0; j < 4; ++j) {
        const int row = t * 16 + l4 * 4 + j;
        out[(size_t)row * 256 + col] = fmaxf(acc[nf][j] + gv, 0.f);
      }
    }
  }
}

// ---------------------------------------------------------------------------
extern "C" void kernel_launch(void* const* d_in, const int* in_sizes, int n_in,
                              void* d_out, int out_size, void* d_ws, size_t ws_size,
                              hipStream_t stream) {
  const float* x          = (const float*)d_in[0];
  const int*   edge_index = (const int*)d_in[1];
  // d_in[2] = batch_vec (row/400 computed inline), d_in[3] = edge_slices: unused
  const float* W1     = (const float*)d_in[4];
  const float* b1     = (const float*)d_in[5];
  const float* W2     = (const float*)d_in[6];
  const float* b2     = (const float*)d_in[7];
  const float* t_tri0 = (const float*)d_in[8];
  const float* t_gau0 = (const float*)d_in[9];
  const float* sig0   = (const float*)d_in[10];
  const float* W_lin0 = (const float*)d_in[11];
  const float* b_lin0 = (const float*)d_in[12];
  const float* c_rh0  = (const float*)d_in[13];
  const float* r_rh0  = (const float*)d_in[14];
  const float* t_tri1 = (const float*)d_in[15];
  const float* t_gau1 = (const float*)d_in[16];
  const float* sig1   = (const float*)d_in[17];
  const float* W_lin1 = (const float*)d_in[18];
  const float* b_lin1 = (const float*)d_in[19];
  const float* c_rh1  = (const float*)d_in[20];
  const float* r_rh1  = (const float*)d_in[21];
  const float* W_out  = (const float*)d_in[22];
  const float* b_out  = (const float*)d_in[23];
  float* out = (float*)d_out;

  // workspace layout (16B-aligned):
  // fv 1.6M | unp 4K | G 128K | (gap) | Wt2 176K | Wt1c 32K | ext 9.8M | xb 26M
  char* base = (char*)d_ws;
  float* fv            = (float*)(base + 0);
  float* unp           = (float*)(base + 1638400);
  float* G             = (float*)(base + 1642496);
  unsigned short* Wt2  = (unsigned short*)(base + 1773824);
  unsigned short* Wt1c = (unsigned short*)(base + 1970432);
  unsigned short* ext  = (unsigned short*)(base + 2003200);
  unsigned short* xb   = (unsigned short*)(base + 11833600);
  const size_t ws_need_xb = 11833600 + (size_t)N_NODES * F_IN * 2;  // ~38 MB
  const int use_xb = ws_size >= ws_need_xb ? 1 : 0;

  hipMemsetAsync(unp, 0, N_GRAPHS * 8 * sizeof(float), stream);
  k_wt<<<(KTOT * 256 + F_IN * HID) / 256, 256, 0, stream>>>(W_out, W1, Wt2, Wt1c);
  k_fv<<<N_NODES / 64, 256, 0, stream>>>(
      x, Wt1c, b1, W2, b2,
      t_tri0, t_gau0, sig0, W_lin0, b_lin0, c_rh0, r_rh0,
      fv, ext, xb, use_xb);
  k_unpaired<<<N_GRAPHS * 8, 256, 0, stream>>>(edge_index, fv, unp);
  k_g1G<<<N_GRAPHS, 256, 0, stream>>>(unp, t_tri1, t_gau1, sig1,
                                      W_lin1, b_lin1, c_rh1, r_rh1,
                                      W_out, b_out, G);
  k_out_mfma<<<512, 256, 0, stream>>>(x, xb, ext, Wt2, G, out, use_xb);
}

// Round 9
// 73.340 us; speedup vs baseline: 1.1798x; 1.0439x over previous
//
#include <hip/hip_runtime.h>

#define N_GRAPHS 128
#define NODES_PER 400
#define EDGES_PER 6400
#define N_NODES (N_GRAPHS * NODES_PER)   // 51200
#define N_EDGES (N_GRAPHS * EDGES_PER)   // 819200
#define F_IN 256
#define HID 64
#define FEAT 96                          // K * 4 * D = 8*4*3
#define KTOT 352                         // 256 + 96 = 11 * 32 exactly

typedef __attribute__((ext_vector_type(8))) short bf16x8;   // MFMA A/B frag (4 VGPRs)
typedef __attribute__((ext_vector_type(4))) float f32x4;    // MFMA C/D frag

union u4b8 { uint4 u; bf16x8 v; };

// float -> bf16 round-to-nearest-even (finite inputs only)
__device__ __forceinline__ unsigned short f2b(float f) {
  union { float f; unsigned int u; } c; c.f = f;
  const unsigned int r = c.u + 0x7FFFu + ((c.u >> 16) & 1u);
  return (unsigned short)(r >> 16);
}

// ---------------------------------------------------------------------------
// coordinate transform: one (fun, d) feature for persistence pair (x0, x1)
// ---------------------------------------------------------------------------
__device__ __forceinline__ float coord_one(
    int fun, int d, float x0, float x1,
    const float* __restrict__ t_tri, const float* __restrict__ t_gau,
    const float* __restrict__ sig, const float* __restrict__ W_lin,
    const float* __restrict__ b_lin, const float* __restrict__ c_rh,
    const float* __restrict__ r_rh) {
  if (fun == 0) {
    return fmaxf(x1 - fabsf(t_tri[d] - x0), 0.f);
  } else if (fun == 1) {
    const float dx = x0 - t_gau[d * 2 + 0];
    const float dy = x1 - t_gau[d * 2 + 1];
    const float s = sig[0];
    return expf(-(dx * dx + dy * dy) / (2.f * s * s));
  } else if (fun == 2) {
    return x0 * W_lin[d] + x1 * W_lin[3 + d] + b_lin[d];
  } else {
    const float l1 = fabsf(x0 - c_rh[d]) + fabsf(x1 - c_rh[d]);
    return 1.f / (1.f + l1) - 1.f / (1.f + fabsf(fabsf(r_rh[0]) - l1));
  }
}

// ---------------------------------------------------------------------------
// Kernel 0: chunked bf16 B operands.
//   Wt2 : (k,c) of W_out^T at [((k>>3)*256 + c)*8 + (k&7)], k < 352
//   Wt1c: (k,c) of W1^T    at [((k>>3)*64  + c)*8 + (k&7)]
// -> B-frag load = one contiguous 16B per lane.
// ---------------------------------------------------------------------------
__global__ __launch_bounds__(256) void k_wt(
    const float* __restrict__ W_out, const float* __restrict__ W1,
    unsigned short* __restrict__ Wt2, unsigned short* __restrict__ Wt1c) {
  const int idx = blockIdx.x * 256 + threadIdx.x;
  if (idx < KTOT * 256) {
    const int k = idx >> 8, c = idx & 255;
    Wt2[((size_t)(k >> 3) * 256 + c) * 8 + (k & 7)] = f2b(W_out[idx]);
  } else {
    const int j = idx - KTOT * 256;       // < 256*64
    const int k = j >> 6, c = j & 63;     // W1[k][c]
    Wt1c[((size_t)(k >> 3) * 64 + c) * 8 + (k & 7)] = f2b(W1[j]);
  }
}

// ---------------------------------------------------------------------------
// Kernel 1: fv = relu(relu(x @ W1 + b1) @ W2 + b2), fused with xb + ext.
// (reg A-frags, per-wave B from L2-resident Wt1c; near HBM floor)
// ---------------------------------------------------------------------------
__global__ __launch_bounds__(256, 3) void k_fv(
    const float* __restrict__ x, const unsigned short* __restrict__ Wt1c,
    const float* __restrict__ b1, const float* __restrict__ W2,
    const float* __restrict__ b2,
    const float* __restrict__ t_tri, const float* __restrict__ t_gau,
    const float* __restrict__ sig, const float* __restrict__ W_lin,
    const float* __restrict__ b_lin, const float* __restrict__ c_rh,
    const float* __restrict__ r_rh,
    float* __restrict__ fv, unsigned short* __restrict__ ext,
    unsigned short* __restrict__ xb, const int write_xb) {
  __shared__ float W2s[HID * 8];
  __shared__ float Hs[4][16][68];
  const int tid = threadIdx.x;
  const int wave = tid >> 6, lane = tid & 63;
  const int l15 = lane & 15, l4 = lane >> 4;
  const int n0 = blockIdx.x * 64;

  W2s[tid] = W2[tid];
  W2s[tid + 256] = W2[tid + 256];
  __syncthreads();

  const int arow = n0 + wave * 16 + l15;
  bf16x8 afr[8];
  #pragma unroll
  for (int kt = 0; kt < 8; ++kt) {
    const size_t go = (size_t)arow * F_IN + kt * 32 + l4 * 8;
    const float4 f0 = *(const float4*)&x[go];
    const float4 f1 = *(const float4*)&x[go + 4];
    u4b8 w;
    w.u.x = (unsigned)f2b(f0.x) | ((unsigned)f2b(f0.y) << 16);
    w.u.y = (unsigned)f2b(f0.z) | ((unsigned)f2b(f0.w) << 16);
    w.u.z = (unsigned)f2b(f1.x) | ((unsigned)f2b(f1.y) << 16);
    w.u.w = (unsigned)f2b(f1.z) | ((unsigned)f2b(f1.w) << 16);
    if (write_xb) *(uint4*)&xb[go] = w.u;
    afr[kt] = w.v;
  }

  f32x4 acc[4];
  #pragma unroll
  for (int nf = 0; nf < 4; ++nf) acc[nf] = (f32x4){0.f, 0.f, 0.f, 0.f};
  #pragma unroll
  for (int kt = 0; kt < 8; ++kt) {
    const unsigned short* wb = Wt1c + (size_t)(kt * 4 + l4) * 512;
    #pragma unroll
    for (int nf = 0; nf < 4; ++nf) {
      const bf16x8 b = *(const bf16x8*)&wb[(nf * 16 + l15) * 8];
      acc[nf] = __builtin_amdgcn_mfma_f32_16x16x32_bf16(afr[kt], b, acc[nf], 0, 0, 0);
    }
  }

  #pragma unroll
  for (int nf = 0; nf < 4; ++nf) {
    const int col = nf * 16 + l15;
    const float bb = b1[col];
    #pragma unroll
    for (int j = 0; j < 4; ++j)
      Hs[wave][l4 * 4 + j][col] = fmaxf(acc[nf][j] + bb, 0.f);
  }
  __syncthreads();

  #pragma unroll
  for (int p = tid; p < 512; p += 256) {
    const int row = p >> 3, kk = p & 7;
    const float* hr = Hs[row >> 4][row & 15];
    float s = b2[kk];
    #pragma unroll 8
    for (int j = 0; j < HID; ++j) s = fmaf(hr[j], W2s[j * 8 + kk], s);
    s = fmaxf(s, 0.f);
    const int n = n0 + row;
    fv[(size_t)n * 8 + kk] = s;

    unsigned short o[12] __attribute__((aligned(16)));
    #pragma unroll
    for (int fun = 0; fun < 4; ++fun)
      #pragma unroll
      for (int d = 0; d < 3; ++d)
        o[fun * 3 + d] = f2b(coord_one(fun, d, s, s,
                             t_tri, t_gau, sig, W_lin, b_lin, c_rh, r_rh));
    unsigned short* dst = &ext[(size_t)n * FEAT + kk * 12];
    *(uint2*)&dst[0] = *(const uint2*)&o[0];
    *(uint2*)&dst[4] = *(const uint2*)&o[4];
    *(uint2*)&dst[8] = *(const uint2*)&o[8];
  }
}

// ---------------------------------------------------------------------------
// Kernel 2: per-chunk partial max -> unpP[g][ch][k]. Each block owns one
// (g, ch) slot and writes it UNCONDITIONALLY -> no pre-zero, no atomics,
// deterministic under workspace poison.
// ---------------------------------------------------------------------------
#define CHUNK (EDGES_PER / 8)   // 800
__global__ __launch_bounds__(256) void k_unpaired(
    const int* __restrict__ ei, const float* __restrict__ fv,
    float* __restrict__ unpP) {
  __shared__ float lfv[NODES_PER * 8];
  __shared__ float red[256][8];
  const int g = blockIdx.x >> 3, ch = blockIdx.x & 7;
  const int tid = threadIdx.x;

  for (int i = tid; i < NODES_PER * 2; i += 256)
    *(float4*)&lfv[i * 4] = *(const float4*)&fv[(size_t)g * NODES_PER * 8 + i * 4];
  __syncthreads();

  float lm[8];
  #pragma unroll
  for (int k = 0; k < 8; ++k) lm[k] = 0.f;
  const int e0 = g * EDGES_PER + ch * CHUNK;
  for (int e = e0 + tid; e < e0 + CHUNK; e += 256) {
    const int a = ei[e] - g * NODES_PER;
    const int b = ei[N_EDGES + e] - g * NODES_PER;
    const float4 a0 = *(const float4*)&lfv[a * 8];
    const float4 a1 = *(const float4*)&lfv[a * 8 + 4];
    const float4 b0 = *(const float4*)&lfv[b * 8];
    const float4 b1 = *(const float4*)&lfv[b * 8 + 4];
    lm[0] = fmaxf(lm[0], fmaxf(a0.x, b0.x));
    lm[1] = fmaxf(lm[1], fmaxf(a0.y, b0.y));
    lm[2] = fmaxf(lm[2], fmaxf(a0.z, b0.z));
    lm[3] = fmaxf(lm[3], fmaxf(a0.w, b0.w));
    lm[4] = fmaxf(lm[4], fmaxf(a1.x, b1.x));
    lm[5] = fmaxf(lm[5], fmaxf(a1.y, b1.y));
    lm[6] = fmaxf(lm[6], fmaxf(a1.z, b1.z));
    lm[7] = fmaxf(lm[7], fmaxf(a1.w, b1.w));
  }
  #pragma unroll
  for (int k = 0; k < 8; ++k) red[tid][k] = lm[k];
  __syncthreads();
  for (int s = 128; s > 0; s >>= 1) {
    if (tid < s) {
      #pragma unroll
      for (int k = 0; k < 8; ++k)
        red[tid][k] = fmaxf(red[tid][k], red[tid + s][k]);
    }
    __syncthreads();
  }
  if (tid < 8) unpP[(size_t)(g * 8 + ch) * 8 + tid] = red[0][tid];
}

// ---------------------------------------------------------------------------
// Kernel 3: reduce unpP chunks -> u[k]; G[g][c] = b_out[c] +
//           sum_t feat1[g][t] * W_out[352+t][c]   (g1 segment fold, fp32)
// ---------------------------------------------------------------------------
__global__ __launch_bounds__(256) void k_g1G(
    const float* __restrict__ unpP, const float* __restrict__ t_tri,
    const float* __restrict__ t_gau, const float* __restrict__ sig,
    const float* __restrict__ W_lin, const float* __restrict__ b_lin,
    const float* __restrict__ c_rh, const float* __restrict__ r_rh,
    const float* __restrict__ W_out, const float* __restrict__ b_out,
    float* __restrict__ G) {
  const int g = blockIdx.x;
  const int t = threadIdx.x;  // 0..255
  __shared__ float u[8];
  __shared__ float feat[96];
  if (t < 8) {
    float m = 0.f;
    #pragma unroll
    for (int ch = 0; ch < 8; ++ch)
      m = fmaxf(m, unpP[(size_t)(g * 8 + ch) * 8 + t]);
    u[t] = m;
  }
  __syncthreads();
  if (t < 96) {
    const float mask = (u[0] != 0.f || u[1] != 0.f || u[2] != 0.f ||
                        u[3] != 0.f || u[4] != 0.f || u[5] != 0.f ||
                        u[6] != 0.f || u[7] != 0.f) ? 1.f : 0.f;
    const int k = t / 12;
    const int fun = (t % 12) / 3;
    const int d = t % 3;
    feat[t] = mask * coord_one(fun, d, u[k], 0.f,
                               t_tri, t_gau, sig, W_lin, b_lin, c_rh, r_rh);
  }
  __syncthreads();
  float s = b_out[t];
  #pragma unroll 4
  for (int f = 0; f < 96; ++f)
    s = fmaf(feat[f], W_out[(size_t)(352 + f) * 256 + t], s);
  G[g * 256 + t] = s;
}

// ---------------------------------------------------------------------------
// Kernel 4: out = relu([x|act0] @ W_out[0:352] + G[batch])  via MFMA.
// BARRIER-FREE, LDS-FREE, B-IN-REGISTERS (round-8 structure, unchanged):
// 512 blocks x 4 waves; wave w owns col-quarter w with its full B-slice
// (44 bf16x8 = 176 VGPR) loaded once; grid-stride over 16-row tiles.
// ---------------------------------------------------------------------------
__global__ __launch_bounds__(256, 2) void k_out_mfma(
    const float* __restrict__ x, const unsigned short* __restrict__ xb,
    const unsigned short* __restrict__ ext,
    const unsigned short* __restrict__ Wt2, const float* __restrict__ G,
    float* __restrict__ out, const int use_xb) {
  const int tid = threadIdx.x;
  const int wave = tid >> 6, lane = tid & 63;
  const int l15 = lane & 15, l4 = lane >> 4;
  const int q = wave;                       // col-quarter owned by this wave

  // ---- load persistent B slice: 44 frags (ks 0..10 x nf 0..3) ----
  bf16x8 b[11][4];
  #pragma unroll
  for (int ks = 0; ks < 11; ++ks)
    #pragma unroll
    for (int nf = 0; nf < 4; ++nf)
      b[ks][nf] = *(const bf16x8*)
          &Wt2[((size_t)(ks * 4 + l4) * 256 + q * 64 + nf * 16 + l15) * 8];

  for (int t = blockIdx.x; t < N_NODES / 16; t += gridDim.x) {
    const int arow = t * 16 + l15;
    const int gidx = t / 25;                // 400 = 25*16: graph of this tile

    // ---- A frags: 11 contiguous 16B loads (x | ext segments) ----
    bf16x8 a[11];
    if (use_xb) {
      #pragma unroll
      for (int ks = 0; ks < 8; ++ks)
        a[ks] = *(const bf16x8*)&xb[(size_t)arow * F_IN + ks * 32 + l4 * 8];
    } else {
      #pragma unroll
      for (int ks = 0; ks < 8; ++ks) {
        const size_t go = (size_t)arow * F_IN + ks * 32 + l4 * 8;
        const float4 f0 = *(const float4*)&x[go];
        const float4 f1 = *(const float4*)&x[go + 4];
        u4b8 w;
        w.u.x = (unsigned)f2b(f0.x) | ((unsigned)f2b(f0.y) << 16);
        w.u.y = (unsigned)f2b(f0.z) | ((unsigned)f2b(f0.w) << 16);
        w.u.z = (unsigned)f2b(f1.x) | ((unsigned)f2b(f1.y) << 16);
        w.u.w = (unsigned)f2b(f1.z) | ((unsigned)f2b(f1.w) << 16);
        a[ks] = w.v;
      }
    }
    #pragma unroll
    for (int ks = 8; ks < 11; ++ks)
      a[ks] = *(const bf16x8*)&ext[(size_t)arow * FEAT + (ks - 8) * 32 + l4 * 8];

    // ---- 44 MFMA ----
    f32x4 acc[4];
    #pragma unroll
    for (int nf = 0; nf < 4; ++nf) acc[nf] = (f32x4){0.f, 0.f, 0.f, 0.f};
    #pragma unroll
    for (int ks = 0; ks < 11; ++ks)
      #pragma unroll
      for (int nf = 0; nf < 4; ++nf)
        acc[nf] = __builtin_amdgcn_mfma_f32_16x16x32_bf16(
            a[ks], b[ks][nf], acc[nf], 0, 0, 0);

    // ---- epilogue: + G[graph] (bias + g1 fold), relu, store ----
    #pragma unroll
    for (int nf = 0; nf < 4; ++nf) {
      const int col = q * 64 + nf * 16 + l15;
      const float gv = G[gidx * 256 + col];
      #pragma unroll
      for (int j = 0; j < 4; ++j) {
        const int row = t * 16 + l4 * 4 + j;
        out[(size_t)row * 256 + col] = fmaxf(acc[nf][j] + gv, 0.f);
      }
    }
  }
}

// ---------------------------------------------------------------------------
extern "C" void kernel_launch(void* const* d_in, const int* in_sizes, int n_in,
                              void* d_out, int out_size, void* d_ws, size_t ws_size,
                              hipStream_t stream) {
  const float* x          = (const float*)d_in[0];
  const int*   edge_index = (const int*)d_in[1];
  // d_in[2] = batch_vec (row/400 computed inline), d_in[3] = edge_slices: unused
  const float* W1     = (const float*)d_in[4];
  const float* b1     = (const float*)d_in[5];
  const float* W2     = (const float*)d_in[6];
  const float* b2     = (const float*)d_in[7];
  const float* t_tri0 = (const float*)d_in[8];
  const float* t_gau0 = (const float*)d_in[9];
  const float* sig0   = (const float*)d_in[10];
  const float* W_lin0 = (const float*)d_in[11];
  const float* b_lin0 = (const float*)d_in[12];
  const float* c_rh0  = (const float*)d_in[13];
  const float* r_rh0  = (const float*)d_in[14];
  const float* t_tri1 = (const float*)d_in[15];
  const float* t_gau1 = (const float*)d_in[16];
  const float* sig1   = (const float*)d_in[17];
  const float* W_lin1 = (const float*)d_in[18];
  const float* b_lin1 = (const float*)d_in[19];
  const float* c_rh1  = (const float*)d_in[20];
  const float* r_rh1  = (const float*)d_in[21];
  const float* W_out  = (const float*)d_in[22];
  const float* b_out  = (const float*)d_in[23];
  float* out = (float*)d_out;

  // workspace layout (16B-aligned):
  // fv 1.6M | unpP 32K | G 128K | Wt2 176K | Wt1c 32K | ext 9.8M | xb 26M
  char* base = (char*)d_ws;
  float* fv            = (float*)(base + 0);
  float* unpP          = (float*)(base + 1638400);
  float* G             = (float*)(base + 1671168);
  unsigned short* Wt2  = (unsigned short*)(base + 1802240);
  unsigned short* Wt1c = (unsigned short*)(base + 1982464);
  unsigned short* ext  = (unsigned short*)(base + 2015232);
  unsigned short* xb   = (unsigned short*)(base + 11845632);
  const size_t ws_need_xb = 11845632 + (size_t)N_NODES * F_IN * 2;  // ~38 MB
  const int use_xb = ws_size >= ws_need_xb ? 1 : 0;

  k_wt<<<(KTOT * 256 + F_IN * HID) / 256, 256, 0, stream>>>(W_out, W1, Wt2, Wt1c);
  k_fv<<<N_NODES / 64, 256, 0, stream>>>(
      x, Wt1c, b1, W2, b2,
      t_tri0, t_gau0, sig0, W_lin0, b_lin0, c_rh0, r_rh0,
      fv, ext, xb, use_xb);
  k_unpaired<<<N_GRAPHS * 8, 256, 0, stream>>>(edge_index, fv, unpP);
  k_g1G<<<N_GRAPHS, 256, 0, stream>>>(unpP, t_tri1, t_gau1, sig1,
                                      W_lin1, b_lin1, c_rh1, r_rh1,
                                      W_out, b_out, G);
  k_out_mfma<<<512, 256, 0, stream>>>(x, xb, ext, Wt2, G, out, use_xb);
}